// Round 4
// baseline (337.795 us; speedup 1.0000x reference)
//
#include <hip/hip_runtime.h>
#include <cstdint>

typedef unsigned short ushort_t;
typedef __attribute__((ext_vector_type(4))) unsigned short ushort4_t;
typedef __attribute__((ext_vector_type(8))) unsigned short ushort8_t;
typedef __attribute__((ext_vector_type(8))) __bf16 bf16x8;
typedef __attribute__((ext_vector_type(4))) float f32x4;

constexpr int NB = 16;    // batch
constexpr int NC = 256;   // channels C (== E)
constexpr int NN = 4096;  // tokens N = H*W
constexpr int NP = 1024;  // region-proj channels = 2*R*heads
constexpr int NT = 512;   // heads * R (Rq columns of T)
constexpr int NO = 768;   // 3*E rows of Wqkv

static __device__ __forceinline__ ushort_t f2b(float f) {
  uint32_t u = __builtin_bit_cast(uint32_t, f);
  u += 0x7FFFu + ((u >> 16) & 1u);
  return (ushort_t)(u >> 16);
}
static __device__ __forceinline__ float b2f(ushort_t h) {
  return __builtin_bit_cast(float, (uint32_t)h << 16);
}
static __device__ __forceinline__ f32x4 mfma16(bf16x8 a, bf16x8 b, f32x4 c) {
  return __builtin_amdgcn_mfma_f32_16x16x32_bf16(a, b, c, 0, 0, 0);
}
typedef __attribute__((address_space(1))) const unsigned int guint;
typedef __attribute__((address_space(3))) unsigned int luint;
static __device__ __forceinline__ void glds16(const void* g, void* l) {
  __builtin_amdgcn_global_load_lds((guint*)g, (luint*)l, 16, 0, 0);
}

// ---------------------------------------------------------------------------
// Shared GEMM core: 128x128 tile, BK=64, XOR-swizzled LDS (conflict-free
// ds_read_b128), glds16 both operands, 32 MFMA per barrier pair.
// LDS tiles: As/Bs = 128 rows x 64 ushorts (16 KB each).
// Swizzle: global[row][col] lives at LDS[row][col ^ ((row&7)<<3)].
// Staged via linear LDS dest + inverse-swizzled per-lane SOURCE address.
// ---------------------------------------------------------------------------
template <int KITERS>
__device__ __forceinline__ void gemm_core(const ushort_t* __restrict__ Asrc, size_t lda,
                                          const ushort_t* __restrict__ Bsrc, size_t ldb,
                                          ushort_t* As, ushort_t* Bs,
                                          f32x4 (&acc)[4][4], int tid) {
  const int l = tid & 63, w = tid >> 6;
  const int fr = l & 15, kq = (l >> 4) * 8;
  const int rr = l >> 3;                       // row within 8-row wave chunk
  const int sc = ((l & 7) ^ rr) << 3;          // inverse-swizzled source col
  const int swz = (fr & 7) << 3;               // read-side XOR
  const int wm = (w >> 1) * 64, wn = (w & 1) * 64;
#pragma unroll 1
  for (int it = 0; it < KITERS; it++) {
    const size_t k0 = (size_t)it * 64;
#pragma unroll
    for (int i = 0; i < 4; i++) {
      const int row = i * 32 + w * 8 + rr;
      glds16(Asrc + (size_t)row * lda + k0 + sc, As + (i * 32 + w * 8) * 64);
      glds16(Bsrc + (size_t)row * ldb + k0 + sc, Bs + (i * 32 + w * 8) * 64);
    }
    __syncthreads();
#pragma unroll
    for (int ks = 0; ks < 2; ks++) {
      const int col = ks * 32 + kq;
      bf16x8 af[4], bf[4];
#pragma unroll
      for (int f = 0; f < 4; f++) {
        af[f] = *(const bf16x8*)&As[(wm + f * 16 + fr) * 64 + (col ^ swz)];
        bf[f] = *(const bf16x8*)&Bs[(wn + f * 16 + fr) * 64 + (col ^ swz)];
      }
#pragma unroll
      for (int fm = 0; fm < 4; fm++)
#pragma unroll
        for (int fn = 0; fn < 4; fn++)
          acc[fm][fn] = mfma16(af[fm], bf[fn], acc[fm][fn]);
    }
    __syncthreads();
  }
}

// ---------------------------------------------------------------------------
// K0: x (f32 [b][c][n]) -> xb (bf16 [b][c][n]) and xt (bf16 [b][n][c])
// ---------------------------------------------------------------------------
__global__ __launch_bounds__(256) void k0_cvt(const float* __restrict__ x,
                                              ushort_t* __restrict__ xb,
                                              ushort_t* __restrict__ xt) {
  __shared__ ushort_t tr[64][88];
  const int tid = threadIdx.x;
  const int n0 = blockIdx.x * 64, c0 = blockIdx.y * 64, b = blockIdx.z;
  const int cr = (tid >> 4) * 4;
  const int nc4 = (tid & 15) * 4;
#pragma unroll
  for (int i = 0; i < 4; i++) {
    size_t idx = ((size_t)b * NC + c0 + cr + i) * NN + n0 + nc4;
    float4 v = *(const float4*)(x + idx);
    ushort4_t o;
    o[0] = f2b(v.x); o[1] = f2b(v.y); o[2] = f2b(v.z); o[3] = f2b(v.w);
    *(ushort4_t*)(xb + idx) = o;
    tr[nc4 + 0][cr + i] = o[0];
    tr[nc4 + 1][cr + i] = o[1];
    tr[nc4 + 2][cr + i] = o[2];
    tr[nc4 + 3][cr + i] = o[3];
  }
  __syncthreads();
  const int nr = tid >> 2, cc0 = (tid & 3) * 16;
  size_t odx = ((size_t)b * NN + n0 + nr) * NC + c0 + cc0;
  *(ushort8_t*)(xt + odx) = *(const ushort8_t*)&tr[nr][cc0];
  *(ushort8_t*)(xt + odx + 8) = *(const ushort8_t*)&tr[nr][cc0 + 8];
}

// generic f32 -> bf16 (count multiple of 1024)
__global__ __launch_bounds__(256) void cvt_f2b_k(const float* __restrict__ src,
                                                 ushort_t* __restrict__ dst) {
  int i = (blockIdx.x * 256 + threadIdx.x) * 4;
  float4 v = *(const float4*)(src + i);
  ushort4_t o;
  o[0] = f2b(v.x); o[1] = f2b(v.y); o[2] = f2b(v.z); o[3] = f2b(v.w);
  *(ushort4_t*)(dst + i) = o;
}

// ---------------------------------------------------------------------------
// K1: P[b,p,n] = Wrb[p,:]·xt[b,n,:] + br[p]   (bf16 out, pre-softmax)
// ---------------------------------------------------------------------------
__global__ __launch_bounds__(256) void k1_proj(const ushort_t* __restrict__ Wrb,
                                               const ushort_t* __restrict__ xt,
                                               const float* __restrict__ br,
                                               ushort_t* __restrict__ P) {
  __shared__ __align__(16) ushort_t As[128 * 64];
  __shared__ __align__(16) ushort_t Bs[128 * 64];
  const int tid = threadIdx.x;
  const int ord = blockIdx.x;
  const int L = (ord & 7) * 512 + (ord >> 3);
  const int m0 = (L & 7) * 128;
  const int n0 = ((L >> 3) & 31) * 128;
  const int b = L >> 8;
  const int lane = tid & 63, w = tid >> 6;
  const int wm = (w >> 1) * 64, wn = (w & 1) * 64;
  f32x4 acc[4][4] = {};
  gemm_core<4>(Wrb + (size_t)m0 * NC, NC,
               xt + ((size_t)b * NN + n0) * NC, NC, As, Bs, acc, tid);
  const int col = lane & 15, rb = (lane >> 4) * 4;
#pragma unroll
  for (int fm = 0; fm < 4; fm++)
#pragma unroll
    for (int rg = 0; rg < 4; rg++) {
      int row = m0 + wm + fm * 16 + rb + rg;
      float bias = br[row];
#pragma unroll
      for (int fn = 0; fn < 4; fn++) {
        int cc = n0 + wn + fn * 16 + col;
        P[((size_t)b * NP + row) * NN + cc] = f2b(acc[fm][fn][rg] + bias);
      }
    }
}

// ---------------------------------------------------------------------------
// K2: softmax over p (1024) per (b,n) column, in-place; rowsum partials.
// ---------------------------------------------------------------------------
__global__ __launch_bounds__(512) void k2_softmax(ushort_t* __restrict__ P,
                                                  float* __restrict__ sPpart) {
  __shared__ float red[64][64];
  __shared__ float Mf[64], If[64];
  const int tid = threadIdx.x;
  const int n0 = blockIdx.x * 64, b = blockIdx.y;
  const int cg = tid & 7, pg = tid >> 3;
  ushort_t* base = P + (size_t)b * NP * NN + n0 + cg * 8;

  ushort8_t v[16];
  float m[8];
#pragma unroll
  for (int j = 0; j < 8; j++) m[j] = -3.0e38f;
#pragma unroll
  for (int r = 0; r < 16; r++) {
    v[r] = *(const ushort8_t*)(base + (size_t)(pg * 16 + r) * NN);
#pragma unroll
    for (int j = 0; j < 8; j++) m[j] = fmaxf(m[j], b2f(v[r][j]));
  }
#pragma unroll
  for (int j = 0; j < 8; j++) red[pg][cg * 8 + j] = m[j];
  __syncthreads();
  if (tid < 64) {
    float M = -3.0e38f;
    for (int g = 0; g < 64; g++) M = fmaxf(M, red[g][tid]);
    Mf[tid] = M;
  }
  __syncthreads();
  float mj[8], s[8];
#pragma unroll
  for (int j = 0; j < 8; j++) { mj[j] = Mf[cg * 8 + j]; s[j] = 0.f; }
#pragma unroll
  for (int r = 0; r < 16; r++)
#pragma unroll
    for (int j = 0; j < 8; j++) s[j] += __expf(b2f(v[r][j]) - mj[j]);
#pragma unroll
  for (int j = 0; j < 8; j++) red[pg][cg * 8 + j] = s[j];
  __syncthreads();
  if (tid < 64) {
    float S = 0.f;
    for (int g = 0; g < 64; g++) S += red[g][tid];
    If[tid] = 1.f / S;
  }
  __syncthreads();
  float ij[8];
#pragma unroll
  for (int j = 0; j < 8; j++) ij[j] = If[cg * 8 + j];
#pragma unroll
  for (int r = 0; r < 16; r++) {
    int p = pg * 16 + r;
    ushort8_t o;
    float rs = 0.f;
#pragma unroll
    for (int j = 0; j < 8; j++) {
      float e = __expf(b2f(v[r][j]) - mj[j]) * ij[j];
      o[j] = f2b(e);
      rs += e;
    }
    *(ushort8_t*)(base + (size_t)p * NN) = o;
    rs += __shfl_xor(rs, 1, 64);
    rs += __shfl_xor(rs, 2, 64);
    rs += __shfl_xor(rs, 4, 64);
    if (cg == 0) sPpart[((size_t)blockIdx.x * NB + b) * NP + p] = rs;
  }
}

// K2r: sP[b,p] = sum over 64 n-blocks
__global__ __launch_bounds__(256) void k2r_reduce(const float* __restrict__ sPpart,
                                                  float* __restrict__ sP) {
  int idx = blockIdx.x * 256 + threadIdx.x;
  float s = 0.f;
#pragma unroll 8
  for (int bx = 0; bx < 64; bx++) s += sPpart[(size_t)bx * (NB * NP) + idx];
  sP[idx] = s;
}

// ---------------------------------------------------------------------------
// K3: XR4[ks][b][c][p] = sum_{n in slice ks} xb[b,c,n]·P[b,p,n]. split-K=2.
// ---------------------------------------------------------------------------
__global__ __launch_bounds__(256) void k3_pool(const ushort_t* __restrict__ xb,
                                               const ushort_t* __restrict__ P,
                                               float* __restrict__ XR4) {
  __shared__ __align__(16) ushort_t As[128 * 64];
  __shared__ __align__(16) ushort_t Bs[128 * 64];
  const int tid = threadIdx.x;
  const int ord = blockIdx.x;
  const int L = (ord & 7) * 64 + (ord >> 3);
  const int m0 = (L & 1) * 128;          // c
  const int n0 = ((L >> 1) & 7) * 128;   // p
  const int zz = L >> 4;
  const int b = zz >> 1, ks = zz & 1;
  const int lane = tid & 63, w = tid >> 6;
  const int wm = (w >> 1) * 64, wn = (w & 1) * 64;
  f32x4 acc[4][4] = {};
  const size_t kbeg = (size_t)ks * 2048;
  gemm_core<32>(xb + ((size_t)b * NC + m0) * NN + kbeg, NN,
                P + ((size_t)b * NP + n0) * NN + kbeg, NN, As, Bs, acc, tid);
  const int col = lane & 15, rb = (lane >> 4) * 4;
  float* outp = XR4 + (size_t)(ks * NB + b) * NC * NP;
#pragma unroll
  for (int fm = 0; fm < 4; fm++)
#pragma unroll
    for (int fn = 0; fn < 4; fn++)
#pragma unroll
      for (int rg = 0; rg < 4; rg++) {
        int row = m0 + wm + fm * 16 + rb + rg;
        int cc = n0 + wn + fn * 16 + col;
        outp[(size_t)row * NP + cc] = acc[fm][fn][rg];
      }
}

// ---------------------------------------------------------------------------
// K3r: XRbT[b][p][c] = f2b(XR4[0][b][c][p] + XR4[1][b][c][p])  (transpose)
// ---------------------------------------------------------------------------
__global__ __launch_bounds__(256) void k3r_tr(const float* __restrict__ XR4,
                                              ushort_t* __restrict__ XRbT) {
  __shared__ ushort_t tr[64][72];
  const int tid = threadIdx.x;
  const int p0 = blockIdx.x * 64, c0 = blockIdx.y * 64, b = blockIdx.z;
  const size_t slice = (size_t)NB * NC * NP;
  const int row = tid >> 4, col4 = (tid & 15) * 4;
#pragma unroll
  for (int i = 0; i < 4; i++) {
    int c = row + i * 16;
    size_t idx = ((size_t)b * NC + c0 + c) * NP + p0 + col4;
    float4 v0 = *(const float4*)(XR4 + idx);
    float4 v1 = *(const float4*)(XR4 + idx + slice);
    tr[col4 + 0][c] = f2b(v0.x + v1.x);
    tr[col4 + 1][c] = f2b(v0.y + v1.y);
    tr[col4 + 2][c] = f2b(v0.z + v1.z);
    tr[col4 + 3][c] = f2b(v0.w + v1.w);
  }
  __syncthreads();
  const int prow = tid >> 2, coff = (tid & 3) * 16;
  size_t odx = ((size_t)b * NP + p0 + prow) * NC + c0 + coff;
  *(ushort8_t*)(XRbT + odx) = *(const ushort8_t*)&tr[prow][coff];
  *(ushort8_t*)(XRbT + odx + 8) = *(const ushort8_t*)&tr[prow][coff + 8];
}

// ---------------------------------------------------------------------------
// K4a: QKVRb[b][o][p] = f2b( Wqkvb[o,:]·XRbT[b,p,:] + bqkv[o]·sP[b,p] )
// ---------------------------------------------------------------------------
__global__ __launch_bounds__(256) void k4a_qkvr(const ushort_t* __restrict__ Wqkvb,
                                                const ushort_t* __restrict__ XRbT,
                                                const float* __restrict__ bqkv,
                                                const float* __restrict__ sP,
                                                ushort_t* __restrict__ QKVRb) {
  __shared__ __align__(16) ushort_t As[128 * 64];
  __shared__ __align__(16) ushort_t Bs[128 * 64];
  const int tid = threadIdx.x;
  const int ord = blockIdx.x;
  const int L = (ord & 7) * 96 + (ord >> 3);
  const int m0 = (L % 6) * 128;
  const int rest = L / 6;
  const int n0 = (rest & 7) * 128;
  const int b = rest >> 3;
  const int lane = tid & 63, w = tid >> 6;
  const int wm = (w >> 1) * 64, wn = (w & 1) * 64;
  f32x4 acc[4][4] = {};
  gemm_core<4>(Wqkvb + (size_t)m0 * NC, NC,
               XRbT + ((size_t)b * NP + n0) * NC, NC, As, Bs, acc, tid);
  const int col = lane & 15, rb = (lane >> 4) * 4;
  float spv[4];
#pragma unroll
  for (int fn = 0; fn < 4; fn++) spv[fn] = sP[(size_t)b * NP + n0 + wn + fn * 16 + col];
#pragma unroll
  for (int fm = 0; fm < 4; fm++)
#pragma unroll
    for (int rg = 0; rg < 4; rg++) {
      int row = m0 + wm + fm * 16 + rb + rg;
      float bq = bqkv[row];
#pragma unroll
      for (int fn = 0; fn < 4; fn++) {
        int cc = n0 + wn + fn * 16 + col;
        QKVRb[((size_t)b * NO + row) * NP + cc] = f2b(acc[fm][fn][rg] + bq * spv[fn]);
      }
    }
}

// ---------------------------------------------------------------------------
// K4b: per-(b,h) tiny attention + Wout fold -> Tmb (bf16)
// ---------------------------------------------------------------------------
__global__ __launch_bounds__(256) void k4b_attn(const ushort_t* __restrict__ QKVRb,
                                                const float* __restrict__ Wout,
                                                ushort_t* __restrict__ Tmb) {
  const int b = blockIdx.x >> 3, h = blockIdx.x & 7;
  const int tid = threadIdx.x;
  __shared__ float qf[96][64];       // q(0:32) k(32:64) v(64:96)
  __shared__ float attn_sT[64][65];  // [k][q]
  __shared__ float vals_s[32][64];
#pragma unroll
  for (int i = 0; i < 3; i++) {
    int u = i * 256 + tid;
    int rw = u >> 3, jc = (u & 7) * 8;
    int p0 = h * 128 + ((rw < 32) ? 0 : 64);
    ushort8_t v = *(const ushort8_t*)(QKVRb + ((size_t)b * NO + h * 96 + rw) * NP + p0 + jc);
#pragma unroll
    for (int j = 0; j < 8; j++) qf[rw][jc + j] = b2f(v[j]);
  }
  __syncthreads();
  const int lj = tid & 63;
  const int rq = tid >> 6;
  float kcol[32];
#pragma unroll
  for (int dd = 0; dd < 32; dd++) kcol[dd] = qf[32 + dd][lj];
  const float isc = 0.17677669529663687f;
#pragma unroll
  for (int r = 0; r < 16; r++) {
    int qi = r * 4 + rq;
    float a = 0.f;
#pragma unroll
    for (int dd = 0; dd < 32; dd++) a += qf[dd][qi] * kcol[dd];
    attn_sT[lj][qi] = a * isc;
  }
  __syncthreads();
  if (tid < 64) {
    float m = -3e38f;
    for (int k = 0; k < 64; k++) m = fmaxf(m, attn_sT[k][tid]);
    float s = 0.f;
    for (int k = 0; k < 64; k++) {
      float e = __expf(attn_sT[k][tid] - m);
      attn_sT[k][tid] = e;
      s += e;
    }
    float inv = 1.f / s;
    for (int k = 0; k < 64; k++) attn_sT[k][tid] *= inv;
  }
  __syncthreads();
  float acol[64];
#pragma unroll
  for (int k = 0; k < 64; k++) acol[k] = attn_sT[k][lj];
#pragma unroll
  for (int r = 0; r < 8; r++) {
    int dd = r * 4 + rq;
    float a = 0.f;
#pragma unroll
    for (int k = 0; k < 64; k++) a += qf[64 + dd][k] * acol[k];
    vals_s[dd][lj] = a;
  }
  __syncthreads();
  float vcol[32];
#pragma unroll
  for (int dd = 0; dd < 32; dd++) vcol[dd] = vals_s[dd][lj];
  for (int r = 0; r < 64; r++) {
    int c = r * 4 + rq;
    const float4* wp = (const float4*)(Wout + (size_t)c * NC + h * 32);
    float a = 0.f;
#pragma unroll
    for (int t = 0; t < 8; t++) {
      float4 w = wp[t];
      a += w.x * vcol[t * 4] + w.y * vcol[t * 4 + 1] + w.z * vcol[t * 4 + 2] +
           w.w * vcol[t * 4 + 3];
    }
    Tmb[((size_t)b * NC + c) * NT + h * 64 + lj] = f2b(a);
  }
}

// ---------------------------------------------------------------------------
// K5: out = x + alpha*(Tmb·Pq + bout). A: glds BK=64 swizzled; B: reg-staged
// transpose into pad-72 LDS tile (ds_write_b128, conflict-free b128 reads).
// ---------------------------------------------------------------------------
__global__ __launch_bounds__(256) void k5_out(const float* __restrict__ x,
                                              const ushort_t* __restrict__ P,
                                              const ushort_t* __restrict__ Tmb,
                                              const float* __restrict__ bout,
                                              const float* __restrict__ alpha,
                                              float* __restrict__ out) {
  __shared__ __align__(16) ushort_t As[128 * 64];
  __shared__ __align__(16) ushort_t Bs[128 * 72];
  const int tid = threadIdx.x;
  const int ord = blockIdx.x;
  const int L = (ord & 7) * 128 + (ord >> 3);
  const int m0 = (L & 1) * 128;
  const int n0 = ((L >> 1) & 31) * 128;
  const int b = L >> 6;
  const int lane = tid & 63, w = tid >> 6;
  const int wm = (w >> 1) * 64, wn = (w & 1) * 64;
  const int fr = lane & 15, kq = (lane >> 4) * 8;
  const int rr = lane >> 3, sc = ((lane & 7) ^ rr) << 3;
  const int swz = (fr & 7) << 3;
  const ushort_t* Asrc = Tmb + ((size_t)b * NC + m0) * NT;
  const int kg = tid >> 5, ng = (tid & 31) * 4;  // B stage: 8 k-rows x 4 n
  f32x4 acc[4][4] = {};
  for (int k0 = 0; k0 < NT; k0 += 64) {
#pragma unroll
    for (int i = 0; i < 4; i++) {
      const int row = i * 32 + w * 8 + rr;
      glds16(Asrc + (size_t)row * NT + k0 + sc, As + (i * 32 + w * 8) * 64);
    }
    ushort4_t bv[8];
#pragma unroll
    for (int i = 0; i < 8; i++) {
      int hj = k0 + kg * 8 + i;
      int prow = ((hj >> 6) << 7) + (hj & 63);
      bv[i] = *(const ushort4_t*)(P + ((size_t)b * NP + prow) * NN + n0 + ng);
    }
#pragma unroll
    for (int jj = 0; jj < 4; jj++) {
      ushort8_t pk;
#pragma unroll
      for (int i = 0; i < 8; i++) pk[i] = bv[i][jj];
      *(ushort8_t*)&Bs[(ng + jj) * 72 + kg * 8] = pk;
    }
    __syncthreads();
#pragma unroll
    for (int ks = 0; ks < 2; ks++) {
      const int col = ks * 32 + kq;
      bf16x8 af[4], bf[4];
#pragma unroll
      for (int f = 0; f < 4; f++) {
        af[f] = *(const bf16x8*)&As[(wm + f * 16 + fr) * 64 + (col ^ swz)];
        bf[f] = *(const bf16x8*)&Bs[(wn + f * 16 + fr) * 72 + col];
      }
#pragma unroll
      for (int fm = 0; fm < 4; fm++)
#pragma unroll
        for (int fn = 0; fn < 4; fn++)
          acc[fm][fn] = mfma16(af[fm], bf[fn], acc[fm][fn]);
    }
    __syncthreads();
  }
  const float al = alpha[0];
  const int col = lane & 15, rb = (lane >> 4) * 4;
#pragma unroll
  for (int fm = 0; fm < 4; fm++)
#pragma unroll
    for (int rg = 0; rg < 4; rg++) {
      int row = m0 + wm + fm * 16 + rb + rg;
      float bias = bout[row];
#pragma unroll
      for (int fn = 0; fn < 4; fn++) {
        int cc = n0 + wn + fn * 16 + col;
        size_t idx = ((size_t)b * NC + row) * NN + cc;
        out[idx] = x[idx] + al * (acc[fm][fn][rg] + bias);
      }
    }
}

// ---------------------------------------------------------------------------
extern "C" void kernel_launch(void* const* d_in, const int* in_sizes, int n_in,
                              void* d_out, int out_size, void* d_ws, size_t ws_size,
                              hipStream_t stream) {
  const float* x = (const float*)d_in[0];
  const float* Wqkv = (const float*)d_in[1];
  const float* bqkv = (const float*)d_in[2];
  const float* Wr = (const float*)d_in[3];
  const float* br = (const float*)d_in[4];
  const float* Wout = (const float*)d_in[5];
  const float* bout = (const float*)d_in[6];
  const float* alpha = (const float*)d_in[7];
  float* out = (float*)d_out;

  char* ws = (char*)d_ws;
  ushort_t* P = (ushort_t*)ws;                    // [0, 134217728)
  ushort_t* xb = (ushort_t*)(ws + 134217728);     // 33.5MB (dead after k3)
  ushort_t* XRbT = (ushort_t*)(ws + 134217728);   //   aliases xb: 8.4MB (k3r+)
  ushort_t* xt = (ushort_t*)(ws + 167772160);     // 33.5MB (dead after k1)
  float* XR4 = (float*)(ws + 167772160);          //   aliases xt: 33.5MB
  ushort_t* QKVRb = (ushort_t*)(ws + 167772160);  //   aliases XR4: 25.2MB (k4a+)
  ushort_t* Wrb = (ushort_t*)(ws + 201326592);    // 0.5MB
  float* sPpart = (float*)(ws + 201850880);       // 4.2MB (dead after k2r)
  ushort_t* Wqkvb = (ushort_t*)(ws + 201850880);  //   aliases sPpart: 0.4MB
  float* sP = (float*)(ws + 206045184);           // 64KB
  ushort_t* Tmb = (ushort_t*)(ws + 206110720);    // 4.2MB -> end 210305024

  k0_cvt<<<dim3(64, 4, 16), 256, 0, stream>>>(x, xb, xt);
  cvt_f2b_k<<<256, 256, 0, stream>>>(Wr, Wrb);
  k1_proj<<<4096, 256, 0, stream>>>(Wrb, xt, br, P);
  k2_softmax<<<dim3(64, 16), 512, 0, stream>>>(P, sPpart);
  k2r_reduce<<<64, 256, 0, stream>>>(sPpart, sP);
  cvt_f2b_k<<<192, 256, 0, stream>>>(Wqkv, Wqkvb);  // after k2r (aliases sPpart)
  k3_pool<<<512, 256, 0, stream>>>(xb, P, XR4);
  k3r_tr<<<dim3(16, 4, 16), 256, 0, stream>>>(XR4, XRbT);  // after k3 (aliases xb)
  k4a_qkvr<<<768, 256, 0, stream>>>(Wqkvb, XRbT, bqkv, sP, QKVRb);
  k4b_attn<<<128, 256, 0, stream>>>(QKVRb, Wout, Tmb);
  k5_out<<<1024, 256, 0, stream>>>(x, P, Tmb, bout, alpha, out);
}

// Round 5
// 328.060 us; speedup vs baseline: 1.0297x; 1.0297x over previous
//
#include <hip/hip_runtime.h>
#include <cstdint>

typedef unsigned short ushort_t;
typedef __attribute__((ext_vector_type(4))) unsigned short ushort4_t;
typedef __attribute__((ext_vector_type(8))) unsigned short ushort8_t;
typedef __attribute__((ext_vector_type(8))) __bf16 bf16x8;
typedef __attribute__((ext_vector_type(4))) float f32x4;

constexpr int NB = 16;    // batch
constexpr int NC = 256;   // channels C (== E)
constexpr int NN = 4096;  // tokens N = H*W
constexpr int NP = 1024;  // region-proj channels = 2*R*heads
constexpr int NT = 512;   // heads * R (Rq columns of T)
constexpr int NO = 768;   // 3*E rows of Wqkv

static __device__ __forceinline__ ushort_t f2b(float f) {
  uint32_t u = __builtin_bit_cast(uint32_t, f);
  u += 0x7FFFu + ((u >> 16) & 1u);
  return (ushort_t)(u >> 16);
}
static __device__ __forceinline__ float b2f(ushort_t h) {
  return __builtin_bit_cast(float, (uint32_t)h << 16);
}
static __device__ __forceinline__ f32x4 mfma16(bf16x8 a, bf16x8 b, f32x4 c) {
  return __builtin_amdgcn_mfma_f32_16x16x32_bf16(a, b, c, 0, 0, 0);
}
typedef __attribute__((address_space(1))) const unsigned int guint;
typedef __attribute__((address_space(3))) unsigned int luint;
static __device__ __forceinline__ void glds16(const void* g, void* l) {
  __builtin_amdgcn_global_load_lds((guint*)g, (luint*)l, 16, 0, 0);
}

// ---------------------------------------------------------------------------
// Shared GEMM core: 128x128 tile, BK=64, XOR-swizzled LDS, DOUBLE-BUFFERED
// 2-phase pipeline: STAGE(t+1) issued BEFORE compute(t); ONE barrier per
// K-step (its vmcnt(0) drain overlaps the 32-MFMA phase).
// SH layout: A bufs at [0,8192),[8192,16384); B bufs at [16384,..),[24576,..)
// Swizzle: global[row][col] lives at LDS[row][col ^ ((row&7)<<3)].
// ---------------------------------------------------------------------------
template <int KITERS>
__device__ __forceinline__ void gemm_core(const ushort_t* __restrict__ Asrc, size_t lda,
                                          const ushort_t* __restrict__ Bsrc, size_t ldb,
                                          ushort_t* SH, f32x4 (&acc)[4][4], int tid) {
  const int l = tid & 63, w = tid >> 6;
  const int fr = l & 15, kq = (l >> 4) * 8;
  const int rr = l >> 3;                // row within 8-row wave chunk
  const int sc = ((l & 7) ^ rr) << 3;   // inverse-swizzled source col
  const int swz = (fr & 7) << 3;        // read-side XOR
  const int wm = (w >> 1) * 64, wn = (w & 1) * 64;

  auto STAGE = [&](int bi, size_t k0) {
    ushort_t* Ad = SH + bi * 8192;
    ushort_t* Bd = SH + 16384 + bi * 8192;
#pragma unroll
    for (int i = 0; i < 4; i++) {
      const int row = i * 32 + w * 8 + rr;
      glds16(Asrc + (size_t)row * lda + k0 + sc, Ad + (i * 32 + w * 8) * 64);
      glds16(Bsrc + (size_t)row * ldb + k0 + sc, Bd + (i * 32 + w * 8) * 64);
    }
  };

  STAGE(0, 0);
  __syncthreads();
  int cur = 0;
#pragma unroll 1
  for (int it = 0; it < KITERS; it++) {
    if (it + 1 < KITERS) STAGE(cur ^ 1, (size_t)(it + 1) * 64);
    const ushort_t* Ar = SH + cur * 8192;
    const ushort_t* Br = SH + 16384 + cur * 8192;
#pragma unroll
    for (int ks = 0; ks < 2; ks++) {
      const int col = ks * 32 + kq;
      bf16x8 af[4], bf[4];
#pragma unroll
      for (int f = 0; f < 4; f++) {
        af[f] = *(const bf16x8*)&Ar[(wm + f * 16 + fr) * 64 + (col ^ swz)];
        bf[f] = *(const bf16x8*)&Br[(wn + f * 16 + fr) * 64 + (col ^ swz)];
      }
#pragma unroll
      for (int fm = 0; fm < 4; fm++)
#pragma unroll
        for (int fn = 0; fn < 4; fn++)
          acc[fm][fn] = mfma16(af[fm], bf[fn], acc[fm][fn]);
    }
    __syncthreads();  // drains vmcnt(0): next-tile loads had the MFMA phase to land
    cur ^= 1;
  }
}

// ---------------------------------------------------------------------------
// K0: x (f32 [b][c][n]) -> xb (bf16 [b][c][n]) and xt (bf16 [b][n][c])
// ---------------------------------------------------------------------------
__global__ __launch_bounds__(256) void k0_cvt(const float* __restrict__ x,
                                              ushort_t* __restrict__ xb,
                                              ushort_t* __restrict__ xt) {
  __shared__ ushort_t tr[64][88];
  const int tid = threadIdx.x;
  const int n0 = blockIdx.x * 64, c0 = blockIdx.y * 64, b = blockIdx.z;
  const int cr = (tid >> 4) * 4;
  const int nc4 = (tid & 15) * 4;
#pragma unroll
  for (int i = 0; i < 4; i++) {
    size_t idx = ((size_t)b * NC + c0 + cr + i) * NN + n0 + nc4;
    float4 v = *(const float4*)(x + idx);
    ushort4_t o;
    o[0] = f2b(v.x); o[1] = f2b(v.y); o[2] = f2b(v.z); o[3] = f2b(v.w);
    *(ushort4_t*)(xb + idx) = o;
    tr[nc4 + 0][cr + i] = o[0];
    tr[nc4 + 1][cr + i] = o[1];
    tr[nc4 + 2][cr + i] = o[2];
    tr[nc4 + 3][cr + i] = o[3];
  }
  __syncthreads();
  const int nr = tid >> 2, cc0 = (tid & 3) * 16;
  size_t odx = ((size_t)b * NN + n0 + nr) * NC + c0 + cc0;
  *(ushort8_t*)(xt + odx) = *(const ushort8_t*)&tr[nr][cc0];
  *(ushort8_t*)(xt + odx + 8) = *(const ushort8_t*)&tr[nr][cc0 + 8];
}

// generic f32 -> bf16 (count multiple of 1024)
__global__ __launch_bounds__(256) void cvt_f2b_k(const float* __restrict__ src,
                                                 ushort_t* __restrict__ dst) {
  int i = (blockIdx.x * 256 + threadIdx.x) * 4;
  float4 v = *(const float4*)(src + i);
  ushort4_t o;
  o[0] = f2b(v.x); o[1] = f2b(v.y); o[2] = f2b(v.z); o[3] = f2b(v.w);
  *(ushort4_t*)(dst + i) = o;
}

// ---------------------------------------------------------------------------
// K1: P[b,p,n] = Wrb[p,:]·xt[b,n,:] + br[p]   (bf16 out, pre-softmax)
// Epilogue: f2b+bias into padded LDS (stride 136), then ushort8 16B stores.
// ---------------------------------------------------------------------------
__global__ __launch_bounds__(256) void k1_proj(const ushort_t* __restrict__ Wrb,
                                               const ushort_t* __restrict__ xt,
                                               const float* __restrict__ br,
                                               ushort_t* __restrict__ P) {
  __shared__ __align__(16) ushort_t SH[4 * 8192];
  const int tid = threadIdx.x;
  const int ord = blockIdx.x;
  const int L = (ord & 7) * 512 + (ord >> 3);
  const int m0 = (L & 7) * 128;
  const int n0 = ((L >> 3) & 31) * 128;
  const int b = L >> 8;
  const int lane = tid & 63, w = tid >> 6;
  const int wm = (w >> 1) * 64, wn = (w & 1) * 64;
  f32x4 acc[4][4] = {};
  gemm_core<4>(Wrb + (size_t)m0 * NC, NC,
               xt + ((size_t)b * NN + n0) * NC, NC, SH, acc, tid);
  const int col = lane & 15, rb = (lane >> 4) * 4;
#pragma unroll
  for (int fm = 0; fm < 4; fm++)
#pragma unroll
    for (int rg = 0; rg < 4; rg++) {
      int row = wm + fm * 16 + rb + rg;
      float bias = br[m0 + row];
#pragma unroll
      for (int fn = 0; fn < 4; fn++)
        SH[row * 136 + wn + fn * 16 + col] = f2b(acc[fm][fn][rg] + bias);
    }
  __syncthreads();
  const int orow = tid >> 1, half = tid & 1;
  const ushort_t* src = &SH[orow * 136 + half * 64];
  ushort_t* dst = P + ((size_t)b * NP + m0 + orow) * NN + n0 + half * 64;
#pragma unroll
  for (int j = 0; j < 8; j++)
    *(ushort8_t*)(dst + j * 8) = *(const ushort8_t*)(src + j * 8);
}

// ---------------------------------------------------------------------------
// K2: softmax over p (1024) per (b,n) column, in-place; rowsum partials.
// ---------------------------------------------------------------------------
__global__ __launch_bounds__(512) void k2_softmax(ushort_t* __restrict__ P,
                                                  float* __restrict__ sPpart) {
  __shared__ float red[64][64];
  __shared__ float Mf[64], If[64];
  const int tid = threadIdx.x;
  const int n0 = blockIdx.x * 64, b = blockIdx.y;
  const int cg = tid & 7, pg = tid >> 3;
  ushort_t* base = P + (size_t)b * NP * NN + n0 + cg * 8;

  ushort8_t v[16];
  float m[8];
#pragma unroll
  for (int j = 0; j < 8; j++) m[j] = -3.0e38f;
#pragma unroll
  for (int r = 0; r < 16; r++) {
    v[r] = *(const ushort8_t*)(base + (size_t)(pg * 16 + r) * NN);
#pragma unroll
    for (int j = 0; j < 8; j++) m[j] = fmaxf(m[j], b2f(v[r][j]));
  }
#pragma unroll
  for (int j = 0; j < 8; j++) red[pg][cg * 8 + j] = m[j];
  __syncthreads();
  if (tid < 64) {
    float M = -3.0e38f;
    for (int g = 0; g < 64; g++) M = fmaxf(M, red[g][tid]);
    Mf[tid] = M;
  }
  __syncthreads();
  float mj[8], s[8];
#pragma unroll
  for (int j = 0; j < 8; j++) { mj[j] = Mf[cg * 8 + j]; s[j] = 0.f; }
#pragma unroll
  for (int r = 0; r < 16; r++)
#pragma unroll
    for (int j = 0; j < 8; j++) s[j] += __expf(b2f(v[r][j]) - mj[j]);
#pragma unroll
  for (int j = 0; j < 8; j++) red[pg][cg * 8 + j] = s[j];
  __syncthreads();
  if (tid < 64) {
    float S = 0.f;
    for (int g = 0; g < 64; g++) S += red[g][tid];
    If[tid] = 1.f / S;
  }
  __syncthreads();
  float ij[8];
#pragma unroll
  for (int j = 0; j < 8; j++) ij[j] = If[cg * 8 + j];
#pragma unroll
  for (int r = 0; r < 16; r++) {
    int p = pg * 16 + r;
    ushort8_t o;
    float rs = 0.f;
#pragma unroll
    for (int j = 0; j < 8; j++) {
      float e = __expf(b2f(v[r][j]) - mj[j]) * ij[j];
      o[j] = f2b(e);
      rs += e;
    }
    *(ushort8_t*)(base + (size_t)p * NN) = o;
    rs += __shfl_xor(rs, 1, 64);
    rs += __shfl_xor(rs, 2, 64);
    rs += __shfl_xor(rs, 4, 64);
    if (cg == 0) sPpart[((size_t)blockIdx.x * NB + b) * NP + p] = rs;
  }
}

// K2r: sP[b,p] = sum over 64 n-blocks
__global__ __launch_bounds__(256) void k2r_reduce(const float* __restrict__ sPpart,
                                                  float* __restrict__ sP) {
  int idx = blockIdx.x * 256 + threadIdx.x;
  float s = 0.f;
#pragma unroll 8
  for (int bx = 0; bx < 64; bx++) s += sPpart[(size_t)bx * (NB * NP) + idx];
  sP[idx] = s;
}

// ---------------------------------------------------------------------------
// K3: XR4[ks][b][c][p] = sum_{n in slice ks} xb[b,c,n]·P[b,p,n]. split-K=2.
// ---------------------------------------------------------------------------
__global__ __launch_bounds__(256) void k3_pool(const ushort_t* __restrict__ xb,
                                               const ushort_t* __restrict__ P,
                                               float* __restrict__ XR4) {
  __shared__ __align__(16) ushort_t SH[4 * 8192];
  const int tid = threadIdx.x;
  const int ord = blockIdx.x;
  const int L = (ord & 7) * 64 + (ord >> 3);
  const int m0 = (L & 1) * 128;          // c
  const int n0 = ((L >> 1) & 7) * 128;   // p
  const int zz = L >> 4;
  const int b = zz >> 1, ks = zz & 1;
  const int lane = tid & 63, w = tid >> 6;
  const int wm = (w >> 1) * 64, wn = (w & 1) * 64;
  f32x4 acc[4][4] = {};
  const size_t kbeg = (size_t)ks * 2048;
  gemm_core<32>(xb + ((size_t)b * NC + m0) * NN + kbeg, NN,
                P + ((size_t)b * NP + n0) * NN + kbeg, NN, SH, acc, tid);
  const int col = lane & 15, rb = (lane >> 4) * 4;
  float* outp = XR4 + (size_t)(ks * NB + b) * NC * NP;
#pragma unroll
  for (int fm = 0; fm < 4; fm++)
#pragma unroll
    for (int fn = 0; fn < 4; fn++)
#pragma unroll
      for (int rg = 0; rg < 4; rg++) {
        int row = m0 + wm + fm * 16 + rb + rg;
        int cc = n0 + wn + fn * 16 + col;
        outp[(size_t)row * NP + cc] = acc[fm][fn][rg];
      }
}

// ---------------------------------------------------------------------------
// K3r: XRbT[b][p][c] = f2b(XR4[0][b][c][p] + XR4[1][b][c][p])  (transpose)
// ---------------------------------------------------------------------------
__global__ __launch_bounds__(256) void k3r_tr(const float* __restrict__ XR4,
                                              ushort_t* __restrict__ XRbT) {
  __shared__ ushort_t tr[64][72];
  const int tid = threadIdx.x;
  const int p0 = blockIdx.x * 64, c0 = blockIdx.y * 64, b = blockIdx.z;
  const size_t slice = (size_t)NB * NC * NP;
  const int row = tid >> 4, col4 = (tid & 15) * 4;
#pragma unroll
  for (int i = 0; i < 4; i++) {
    int c = row + i * 16;
    size_t idx = ((size_t)b * NC + c0 + c) * NP + p0 + col4;
    float4 v0 = *(const float4*)(XR4 + idx);
    float4 v1 = *(const float4*)(XR4 + idx + slice);
    tr[col4 + 0][c] = f2b(v0.x + v1.x);
    tr[col4 + 1][c] = f2b(v0.y + v1.y);
    tr[col4 + 2][c] = f2b(v0.z + v1.z);
    tr[col4 + 3][c] = f2b(v0.w + v1.w);
  }
  __syncthreads();
  const int prow = tid >> 2, coff = (tid & 3) * 16;
  size_t odx = ((size_t)b * NP + p0 + prow) * NC + c0 + coff;
  *(ushort8_t*)(XRbT + odx) = *(const ushort8_t*)&tr[prow][coff];
  *(ushort8_t*)(XRbT + odx + 8) = *(const ushort8_t*)&tr[prow][coff + 8];
}

// ---------------------------------------------------------------------------
// K4a: QKVRb[b][o][p] = f2b( Wqkvb[o,:]·XRbT[b,p,:] + bqkv[o]·sP[b,p] )
// ---------------------------------------------------------------------------
__global__ __launch_bounds__(256) void k4a_qkvr(const ushort_t* __restrict__ Wqkvb,
                                                const ushort_t* __restrict__ XRbT,
                                                const float* __restrict__ bqkv,
                                                const float* __restrict__ sP,
                                                ushort_t* __restrict__ QKVRb) {
  __shared__ __align__(16) ushort_t SH[4 * 8192];
  const int tid = threadIdx.x;
  const int ord = blockIdx.x;
  const int L = (ord & 7) * 96 + (ord >> 3);
  const int m0 = (L % 6) * 128;
  const int rest = L / 6;
  const int n0 = (rest & 7) * 128;
  const int b = rest >> 3;
  const int lane = tid & 63, w = tid >> 6;
  const int wm = (w >> 1) * 64, wn = (w & 1) * 64;
  f32x4 acc[4][4] = {};
  gemm_core<4>(Wqkvb + (size_t)m0 * NC, NC,
               XRbT + ((size_t)b * NP + n0) * NC, NC, SH, acc, tid);
  const int col = lane & 15, rb = (lane >> 4) * 4;
  float spv[4];
#pragma unroll
  for (int fn = 0; fn < 4; fn++) spv[fn] = sP[(size_t)b * NP + n0 + wn + fn * 16 + col];
#pragma unroll
  for (int fm = 0; fm < 4; fm++)
#pragma unroll
    for (int rg = 0; rg < 4; rg++) {
      int row = m0 + wm + fm * 16 + rb + rg;
      float bq = bqkv[row];
#pragma unroll
      for (int fn = 0; fn < 4; fn++) {
        int cc = n0 + wn + fn * 16 + col;
        QKVRb[((size_t)b * NO + row) * NP + cc] = f2b(acc[fm][fn][rg] + bq * spv[fn]);
      }
    }
}

// ---------------------------------------------------------------------------
// K4b: per-(b,h) tiny attention + Wout fold -> Tmb (bf16)
// ---------------------------------------------------------------------------
__global__ __launch_bounds__(256) void k4b_attn(const ushort_t* __restrict__ QKVRb,
                                                const float* __restrict__ Wout,
                                                ushort_t* __restrict__ Tmb) {
  const int b = blockIdx.x >> 3, h = blockIdx.x & 7;
  const int tid = threadIdx.x;
  __shared__ float qf[96][64];       // q(0:32) k(32:64) v(64:96)
  __shared__ float attn_sT[64][65];  // [k][q]
  __shared__ float vals_s[32][64];
#pragma unroll
  for (int i = 0; i < 3; i++) {
    int u = i * 256 + tid;
    int rw = u >> 3, jc = (u & 7) * 8;
    int p0 = h * 128 + ((rw < 32) ? 0 : 64);
    ushort8_t v = *(const ushort8_t*)(QKVRb + ((size_t)b * NO + h * 96 + rw) * NP + p0 + jc);
#pragma unroll
    for (int j = 0; j < 8; j++) qf[rw][jc + j] = b2f(v[j]);
  }
  __syncthreads();
  const int lj = tid & 63;
  const int rq = tid >> 6;
  float kcol[32];
#pragma unroll
  for (int dd = 0; dd < 32; dd++) kcol[dd] = qf[32 + dd][lj];
  const float isc = 0.17677669529663687f;
#pragma unroll
  for (int r = 0; r < 16; r++) {
    int qi = r * 4 + rq;
    float a = 0.f;
#pragma unroll
    for (int dd = 0; dd < 32; dd++) a += qf[dd][qi] * kcol[dd];
    attn_sT[lj][qi] = a * isc;
  }
  __syncthreads();
  if (tid < 64) {
    float m = -3e38f;
    for (int k = 0; k < 64; k++) m = fmaxf(m, attn_sT[k][tid]);
    float s = 0.f;
    for (int k = 0; k < 64; k++) {
      float e = __expf(attn_sT[k][tid] - m);
      attn_sT[k][tid] = e;
      s += e;
    }
    float inv = 1.f / s;
    for (int k = 0; k < 64; k++) attn_sT[k][tid] *= inv;
  }
  __syncthreads();
  float acol[64];
#pragma unroll
  for (int k = 0; k < 64; k++) acol[k] = attn_sT[k][lj];
#pragma unroll
  for (int r = 0; r < 8; r++) {
    int dd = r * 4 + rq;
    float a = 0.f;
#pragma unroll
    for (int k = 0; k < 64; k++) a += qf[64 + dd][k] * acol[k];
    vals_s[dd][lj] = a;
  }
  __syncthreads();
  float vcol[32];
#pragma unroll
  for (int dd = 0; dd < 32; dd++) vcol[dd] = vals_s[dd][lj];
  for (int r = 0; r < 64; r++) {
    int c = r * 4 + rq;
    const float4* wp = (const float4*)(Wout + (size_t)c * NC + h * 32);
    float a = 0.f;
#pragma unroll
    for (int t = 0; t < 8; t++) {
      float4 w = wp[t];
      a += w.x * vcol[t * 4] + w.y * vcol[t * 4 + 1] + w.z * vcol[t * 4 + 2] +
           w.w * vcol[t * 4 + 3];
    }
    Tmb[((size_t)b * NC + c) * NT + h * 64 + lj] = f2b(a);
  }
}

// ---------------------------------------------------------------------------
// K5: out = x + alpha*(Tmb·Pq + bout). Pipelined: A glds dbuf; B reg-staged
// T14-style (load-early / ds_write-late) into pad-72 dbuf LDS tile.
// ---------------------------------------------------------------------------
__global__ __launch_bounds__(256) void k5_out(const float* __restrict__ x,
                                              const ushort_t* __restrict__ P,
                                              const ushort_t* __restrict__ Tmb,
                                              const float* __restrict__ bout,
                                              const float* __restrict__ alpha,
                                              float* __restrict__ out) {
  __shared__ __align__(16) ushort_t Ash[2 * 8192];  // 32 KB
  __shared__ __align__(16) ushort_t Bsh[2 * 9216];  // 36 KB (128 rows x 72)
  const int tid = threadIdx.x;
  const int ord = blockIdx.x;
  const int L = (ord & 7) * 128 + (ord >> 3);
  const int m0 = (L & 1) * 128;
  const int n0 = ((L >> 1) & 31) * 128;
  const int b = L >> 6;
  const int lane = tid & 63, w = tid >> 6;
  const int wm = (w >> 1) * 64, wn = (w & 1) * 64;
  const int fr = lane & 15, kq = (lane >> 4) * 8;
  const int rr = lane >> 3, sc = ((lane & 7) ^ rr) << 3;
  const int swz = (fr & 7) << 3;
  const ushort_t* Asrc = Tmb + ((size_t)b * NC + m0) * NT;
  const int kg = tid >> 5, ng = (tid & 31) * 4;  // B stage: 8 k-rows x 4 n
  f32x4 acc[4][4] = {};
  ushort4_t bv[8];

  auto A_STAGE = [&](int bi, int k0) {
    ushort_t* Ad = Ash + bi * 8192;
#pragma unroll
    for (int i = 0; i < 4; i++) {
      const int row = i * 32 + w * 8 + rr;
      glds16(Asrc + (size_t)row * NT + k0 + sc, Ad + (i * 32 + w * 8) * 64);
    }
  };
  auto B_LOAD = [&](int k0) {
#pragma unroll
    for (int i = 0; i < 8; i++) {
      int hj = k0 + kg * 8 + i;
      int prow = ((hj >> 6) << 7) + (hj & 63);
      bv[i] = *(const ushort4_t*)(P + ((size_t)b * NP + prow) * NN + n0 + ng);
    }
  };
  auto B_WRITE = [&](int bi) {
#pragma unroll
    for (int jj = 0; jj < 4; jj++) {
      ushort8_t pk;
#pragma unroll
      for (int i = 0; i < 8; i++) pk[i] = bv[i][jj];
      *(ushort8_t*)&Bsh[bi * 9216 + (ng + jj) * 72 + kg * 8] = pk;
    }
  };

  A_STAGE(0, 0);
  B_LOAD(0);
  B_WRITE(0);
  __syncthreads();
  int cur = 0;
#pragma unroll 1
  for (int it = 0; it < 8; it++) {
    if (it + 1 < 8) {
      A_STAGE(cur ^ 1, (it + 1) * 64);
      B_LOAD((it + 1) * 64);
    }
    const ushort_t* Ar = Ash + cur * 8192;
    const ushort_t* Br = Bsh + cur * 9216;
#pragma unroll
    for (int ks = 0; ks < 2; ks++) {
      const int col = ks * 32 + kq;
      bf16x8 af[4], bf[4];
#pragma unroll
      for (int f = 0; f < 4; f++) {
        af[f] = *(const bf16x8*)&Ar[(wm + f * 16 + fr) * 64 + (col ^ swz)];
        bf[f] = *(const bf16x8*)&Br[(wn + f * 16 + fr) * 72 + col];
      }
#pragma unroll
      for (int fm = 0; fm < 4; fm++)
#pragma unroll
        for (int fn = 0; fn < 4; fn++)
          acc[fm][fn] = mfma16(af[fm], bf[fn], acc[fm][fn]);
    }
    if (it + 1 < 8) B_WRITE(cur ^ 1);  // ds_write after compute (T14 write-late)
    __syncthreads();
    cur ^= 1;
  }
  const float al = alpha[0];
  const int col = lane & 15, rb = (lane >> 4) * 4;
#pragma unroll
  for (int fm = 0; fm < 4; fm++)
#pragma unroll
    for (int rg = 0; rg < 4; rg++) {
      int row = m0 + wm + fm * 16 + rb + rg;
      float bias = bout[row];
#pragma unroll
      for (int fn = 0; fn < 4; fn++) {
        int cc = n0 + wn + fn * 16 + col;
        size_t idx = ((size_t)b * NC + row) * NN + cc;
        out[idx] = x[idx] + al * (acc[fm][fn][rg] + bias);
      }
    }
}

// ---------------------------------------------------------------------------
extern "C" void kernel_launch(void* const* d_in, const int* in_sizes, int n_in,
                              void* d_out, int out_size, void* d_ws, size_t ws_size,
                              hipStream_t stream) {
  const float* x = (const float*)d_in[0];
  const float* Wqkv = (const float*)d_in[1];
  const float* bqkv = (const float*)d_in[2];
  const float* Wr = (const float*)d_in[3];
  const float* br = (const float*)d_in[4];
  const float* Wout = (const float*)d_in[5];
  const float* bout = (const float*)d_in[6];
  const float* alpha = (const float*)d_in[7];
  float* out = (float*)d_out;

  char* ws = (char*)d_ws;
  ushort_t* P = (ushort_t*)ws;                    // [0, 134217728)
  ushort_t* xb = (ushort_t*)(ws + 134217728);     // 33.5MB (dead after k3)
  ushort_t* XRbT = (ushort_t*)(ws + 134217728);   //   aliases xb: 8.4MB (k3r+)
  ushort_t* xt = (ushort_t*)(ws + 167772160);     // 33.5MB (dead after k1)
  float* XR4 = (float*)(ws + 167772160);          //   aliases xt: 33.5MB
  ushort_t* QKVRb = (ushort_t*)(ws + 167772160);  //   aliases XR4: 25.2MB (k4a+)
  ushort_t* Wrb = (ushort_t*)(ws + 201326592);    // 0.5MB
  float* sPpart = (float*)(ws + 201850880);       // 4.2MB (dead after k2r)
  ushort_t* Wqkvb = (ushort_t*)(ws + 201850880);  //   aliases sPpart: 0.4MB
  float* sP = (float*)(ws + 206045184);           // 64KB
  ushort_t* Tmb = (ushort_t*)(ws + 206110720);    // 4.2MB -> end 210305024

  k0_cvt<<<dim3(64, 4, 16), 256, 0, stream>>>(x, xb, xt);
  cvt_f2b_k<<<256, 256, 0, stream>>>(Wr, Wrb);
  k1_proj<<<4096, 256, 0, stream>>>(Wrb, xt, br, P);
  k2_softmax<<<dim3(64, 16), 512, 0, stream>>>(P, sPpart);
  k2r_reduce<<<64, 256, 0, stream>>>(sPpart, sP);
  cvt_f2b_k<<<192, 256, 0, stream>>>(Wqkv, Wqkvb);  // after k2r (aliases sPpart)
  k3_pool<<<512, 256, 0, stream>>>(xb, P, XR4);
  k3r_tr<<<dim3(16, 4, 16), 256, 0, stream>>>(XR4, XRbT);  // after k3 (aliases xb)
  k4a_qkvr<<<768, 256, 0, stream>>>(Wqkvb, XRbT, bqkv, sP, QKVRb);
  k4b_attn<<<128, 256, 0, stream>>>(QKVRb, Wout, Tmb);
  k5_out<<<1024, 256, 0, stream>>>(x, P, Tmb, bout, alpha, out);
}